// Round 2
// baseline (225.598 us; speedup 1.0000x reference)
//
#include <hip/hip_runtime.h>

typedef _Float16 f16;
typedef _Float16 v8hf __attribute__((ext_vector_type(8)));
typedef _Float16 v4hf __attribute__((ext_vector_type(4)));
typedef _Float16 v2hf __attribute__((ext_vector_type(2)));
typedef float    v4f  __attribute__((ext_vector_type(4)));

#define NPTS 16384
#define PTS  16           // points per workgroup -> M = 6*PTS = 96 site-rows
#define ROWS 96
#define NLAYER_ELEMS 65536  // 256*256 f16 per layer per split

// XOR-swizzled LDS index for logical (row m, f16-col j); row stride 256 f16
// (512 B == 0 mod 128 B). 16B chunks; phys chunk = chunk ^ (m&7). Every access
// in this kernel is contained in one 16B chunk, so data stays contiguous.
__device__ __forceinline__ int swz(int m, int j) {
    return m * 256 + ((((j >> 3) ^ (m & 7)) << 3) | (j & 7));
}

// ---- f32 <-> (lo16, hi16) bit-split helpers via v_perm_b32 (exact) ----------
__device__ __forceinline__ uint32_t pk_lo(float x0, float x1) {
    return __builtin_amdgcn_perm(__float_as_uint(x1), __float_as_uint(x0), 0x05040100u);
}
__device__ __forceinline__ uint32_t pk_hi(float x0, float x1) {
    return __builtin_amdgcn_perm(__float_as_uint(x1), __float_as_uint(x0), 0x07060302u);
}
__device__ __forceinline__ float up0(uint32_t lo, uint32_t hi) {
    return __uint_as_float(__builtin_amdgcn_perm(hi, lo, 0x05040100u));
}
__device__ __forceinline__ float up1(uint32_t lo, uint32_t hi) {
    return __uint_as_float(__builtin_amdgcn_perm(hi, lo, 0x07060302u));
}

// ---------------- prepass: split+transpose W1..W3 into MFMA A-operand order ----
// Bpack[L][ks][n][kk] (f16), kk=k&31, ks=k>>5: lane frag read = 8 contiguous f16.
__global__ void pack_weights(const float* __restrict__ W1, const float* __restrict__ W2,
                             const float* __restrict__ W3, f16* __restrict__ bh,
                             f16* __restrict__ bl) {
    const int L = blockIdx.x >> 3, ks = blockIdx.x & 7, n = threadIdx.x;
    const float* W = (L == 0) ? W1 : (L == 1) ? W2 : W3;
    f16 h[32], l[32];
    #pragma unroll
    for (int kk = 0; kk < 32; ++kk) {
        float w = W[(ks * 32 + kk) * 256 + n];      // coalesced along n
        f16 hh = (f16)w;
        h[kk] = hh;
        l[kk] = (f16)(w - (float)hh);
    }
    size_t off = (size_t)L * NLAYER_ELEMS + (size_t)(ks * 256 + n) * 32;
    #pragma unroll
    for (int i = 0; i < 4; ++i) {
        *(v8hf*)(bh + off + 8 * i) = *(v8hf*)(h + 8 * i);
        *(v8hf*)(bl + off + 8 * i) = *(v8hf*)(l + 8 * i);
    }
}

// ---------------- main kernel --------------------------------------------------
// PTS=16 points/block, 512 threads (8 waves). Wave wv owns neuron cols
// [wv*32, wv*32+32). Channels: 0=val 1=dx 2=dy 3=dt 4=dxx 5=dyy; site-row
// m = c*PTS + p (96 rows = 6 mTiles of 16).
// Hidden GEMM computes Z^T via mfma(A-op=W^T frag, B-op=A^T frag):
//   D row (quad*4+reg) = neuron col n, D col (lane&15) = site-row m.
// Weight fragments are double-buffered in registers (load ks+1 during ks MFMAs).
__global__ __launch_bounds__(512, 2) void pinn_burgers_kernel(
    const float* __restrict__ gx, const float* __restrict__ gy,
    const float* __restrict__ gt, const float* __restrict__ gnu,
    const float* __restrict__ W0, const float* __restrict__ b0,
    const float* __restrict__ b1, const float* __restrict__ b2,
    const float* __restrict__ b3,
    const float* __restrict__ W4, const float* __restrict__ b4,
    const f16* __restrict__ bh, const f16* __restrict__ bl,
    float* __restrict__ out)
{
    extern __shared__ char smem[];
    f16*   Ah  = (f16*)smem;                 // 96*256 f16 = 49152 B (swizzled)
    f16*   Al  = Ah + ROWS * 256;            // 49152 B
    float* red = (float*)(Al + ROWS * 256);  // [PTS][12] = 768 B
    float* pin = red + PTS * 12;             // [4][PTS]  = 256 B

    const int tid  = threadIdx.x;
    const int lane = tid & 63;
    const int wv   = tid >> 6;        // 8 waves
    const int ln   = lane & 15;
    const int quad = lane >> 4;
    const int lnx  = ln & 7;
    const int p0   = blockIdx.x * PTS;

    if (tid < 4 * PTS) {
        int c = tid >> 4, p = tid & 15;
        const float* src = (c == 0) ? gx : (c == 1) ? gy : (c == 2) ? gt : gnu;
        pin[c * PTS + p] = src[p0 + p];
    }
    __syncthreads();

    // Activation-phase lane mapping: lane = (point pa, chunk jb within wave's 32
    // cols). Covers all (16 pt x 32 chunk) units bijectively across 8 waves.
    const int pa    = lane >> 2;          // point 0..15
    const int jb    = lane & 3;           // chunk 0..3
    const int jbase = wv * 32 + jb * 8;   // first of 8 contiguous cols

    // split-f16 store of 8 activation values (feeds next GEMM)
    auto store_split = [&](const float (&A)[8], int c) {
        v8hf hh, ll;
        #pragma unroll
        for (int e = 0; e < 8; ++e) {
            f16 hv = (f16)A[e];
            hh[e] = hv;
            ll[e] = (f16)(A[e] - (float)hv);
        }
        int idx = swz(c * PTS + pa, jbase);
        *(v8hf*)&Ah[idx] = hh;
        *(v8hf*)&Al[idx] = ll;
    };
    // raw f32 bit-split store of 8 values (feeds output layer only)
    auto store_raw = [&](const float (&A)[8], int c) {
        uint4 lo, hi;
        lo.x = pk_lo(A[0], A[1]); lo.y = pk_lo(A[2], A[3]);
        lo.z = pk_lo(A[4], A[5]); lo.w = pk_lo(A[6], A[7]);
        hi.x = pk_hi(A[0], A[1]); hi.y = pk_hi(A[2], A[3]);
        hi.z = pk_hi(A[4], A[5]); hi.w = pk_hi(A[6], A[7]);
        int idx = swz(c * PTS + pa, jbase);
        *(uint4*)&Ah[idx] = lo;
        *(uint4*)&Al[idx] = hi;
    };

    // ---------------- layer 0 (4 -> 256), fp32 VALU, write split f16 ----------
    {
        v4f w0v[2], w1v[2], w2v[2], w3v[2], bbv[2];
        #pragma unroll
        for (int h = 0; h < 2; ++h) {
            w0v[h] = *(const v4f*)(W0 +   0 + jbase + 4 * h);
            w1v[h] = *(const v4f*)(W0 + 256 + jbase + 4 * h);
            w2v[h] = *(const v4f*)(W0 + 512 + jbase + 4 * h);
            w3v[h] = *(const v4f*)(W0 + 768 + jbase + 4 * h);
            bbv[h] = *(const v4f*)(b0 + jbase + 4 * h);
        }
        float hx = pin[0 * PTS + pa];
        float hy = pin[1 * PTS + pa];
        float ht = 2.f * pin[2 * PTS + pa] - 1.f;
        float hn = 2.f * (pin[3 * PTS + pa] - 0.01f) * (1.f / 0.09f) - 1.f;
        float A0[8], A1[8], A2[8], A3[8], A4[8], A5[8];
        #pragma unroll
        for (int e = 0; e < 8; ++e) {
            float w0 = w0v[e >> 2][e & 3];
            float w1 = w1v[e >> 2][e & 3];
            float w2 = w2v[e >> 2][e & 3];
            float w3 = w3v[e >> 2][e & 3];
            float z  = hx * w0 + hy * w1 + ht * w2 + hn * w3 + bbv[e >> 2][e & 3];
            float zx = w0, zy = w1, zt = 2.f * w2;
            float s  = 1.f / (1.f + __expf(-z));
            float g1 = s * (1.f + z * (1.f - s));
            float g2 = s * (1.f - s) * (2.f + z * (1.f - 2.f * s));
            A0[e] = z * s;
            A1[e] = g1 * zx; A2[e] = g1 * zy; A3[e] = g1 * zt;
            A4[e] = g2 * zx * zx; A5[e] = g2 * zy * zy;
        }
        store_split(A0, 0); store_split(A1, 1); store_split(A2, 2);
        store_split(A3, 3); store_split(A4, 4); store_split(A5, 5);
    }
    __syncthreads();

    // ---------------- hidden layers 1..3: split-f16 MFMA ----------------------
    const float* bias_ptr[3] = { b1, b2, b3 };
    for (int L = 0; L < 3; ++L) {
        const f16* __restrict__ bhL = bh + (size_t)L * NLAYER_ELEMS;
        const f16* __restrict__ blL = bl + (size_t)L * NLAYER_ELEMS;
        const float* __restrict__ bv = bias_ptr[L];

        v4f acc[2][6];     // [nTile t][mTile] ; wave owns neuron cols wv*32..+31
        #pragma unroll
        for (int t = 0; t < 2; ++t)
            #pragma unroll
            for (int mt = 0; mt < 6; ++mt)
                acc[t][mt] = (v4f){0.f, 0.f, 0.f, 0.f};

        // register double-buffer for weight fragments
        v8hf w_h[2][2], w_l[2][2];   // [buf][t]
        #pragma unroll
        for (int t = 0; t < 2; ++t) {
            int n = wv * 32 + t * 16 + ln;
            size_t o = (size_t)n * 32 + quad * 8;
            w_h[0][t] = *(const v8hf*)(bhL + o);
            w_l[0][t] = *(const v8hf*)(blL + o);
        }

        #pragma unroll
        for (int ks = 0; ks < 8; ++ks) {
            const int cur = ks & 1, nxt = cur ^ 1;
            if (ks + 1 < 8) {   // prefetch next K-slice's weight fragments
                #pragma unroll
                for (int t = 0; t < 2; ++t) {
                    int n = wv * 32 + t * 16 + ln;
                    size_t o = (size_t)((ks + 1) * 256 + n) * 32 + quad * 8;
                    w_h[nxt][t] = *(const v8hf*)(bhL + o);
                    w_l[nxt][t] = *(const v8hf*)(blL + o);
                }
            }
            // A-fragment LDS reads: chunk (4ks+quad) ^ (ln&7) -> conflict-free
            const int cb = (((4 * ks + quad) ^ lnx) << 3);
            v8hf a_h[6], a_l[6];
            #pragma unroll
            for (int mt = 0; mt < 6; ++mt) {
                const int rb = (mt * 16 + ln) * 256 + cb;
                a_h[mt] = *(const v8hf*)&Ah[rb];
                a_l[mt] = *(const v8hf*)&Al[rb];
            }
            #pragma unroll
            for (int t = 0; t < 2; ++t)
                #pragma unroll
                for (int mt = 0; mt < 6; ++mt) {
                    acc[t][mt] = __builtin_amdgcn_mfma_f32_16x16x32_f16(w_h[cur][t], a_h[mt], acc[t][mt], 0, 0, 0);
                    acc[t][mt] = __builtin_amdgcn_mfma_f32_16x16x32_f16(w_h[cur][t], a_l[mt], acc[t][mt], 0, 0, 0);
                    acc[t][mt] = __builtin_amdgcn_mfma_f32_16x16x32_f16(w_l[cur][t], a_h[mt], acc[t][mt], 0, 0, 0);
                }
        }
        __syncthreads();   // all reads of A done before overwrite

        // epilogue: D row = neuron n (quad*4+reg), D col = site-row m (lane&15).
        // Write raw f32 bits: lo16 -> Ah, hi16 -> Al (exact, cheap).
        #pragma unroll
        for (int t = 0; t < 2; ++t)
            #pragma unroll
            for (int mt = 0; mt < 6; ++mt) {
                v4f a = acc[t][mt];
                int nb = wv * 32 + t * 16 + quad * 4;
                int m  = mt * 16 + ln;
                if (mt == 0) {   // rows 0..15 are the value channel: add bias
                    const float4 bq = *(const float4*)(bv + nb);
                    a[0] += bq.x; a[1] += bq.y; a[2] += bq.z; a[3] += bq.w;
                }
                int idx = swz(m, nb);
                uint2 lo, hi;
                lo.x = pk_lo(a[0], a[1]); lo.y = pk_lo(a[2], a[3]);
                hi.x = pk_hi(a[0], a[1]); hi.y = pk_hi(a[2], a[3]);
                *(uint2*)&Ah[idx] = lo;
                *(uint2*)&Al[idx] = hi;
            }
        // NO barrier: activation below touches only this wave's columns.

        // activation + AD chain, in place (wave-local columns), b128 LDS
        {
            float z0[8], z1[8], z2[8], z3[8], z4[8], z5[8];
            auto load_z = [&](float (&Z)[8], int c) {
                int idx = swz(c * PTS + pa, jbase);
                uint4 lo = *(const uint4*)&Ah[idx];
                uint4 hi = *(const uint4*)&Al[idx];
                Z[0] = up0(lo.x, hi.x); Z[1] = up1(lo.x, hi.x);
                Z[2] = up0(lo.y, hi.y); Z[3] = up1(lo.y, hi.y);
                Z[4] = up0(lo.z, hi.z); Z[5] = up1(lo.z, hi.z);
                Z[6] = up0(lo.w, hi.w); Z[7] = up1(lo.w, hi.w);
            };
            load_z(z0, 0); load_z(z1, 1); load_z(z2, 2);
            load_z(z3, 3); load_z(z4, 4); load_z(z5, 5);

            float A0[8], g1[8], g2[8];
            #pragma unroll
            for (int e = 0; e < 8; ++e) {
                float zz = z0[e];
                float s  = 1.f / (1.f + __expf(-zz));
                A0[e] = zz * s;
                g1[e] = s * (1.f + zz * (1.f - s));
                g2[e] = s * (1.f - s) * (2.f + zz * (1.f - 2.f * s));
            }
            float A1[8], A2[8], A3[8], A4[8], A5[8];
            #pragma unroll
            for (int e = 0; e < 8; ++e) {
                A1[e] = g1[e] * z1[e];
                A2[e] = g1[e] * z2[e];
                A3[e] = g1[e] * z3[e];
                A4[e] = g2[e] * z1[e] * z1[e] + g1[e] * z4[e];
                A5[e] = g2[e] * z2[e] * z2[e] + g1[e] * z5[e];
            }
            if (L < 2) {   // feeds another MFMA layer: split f16
                store_split(A0, 0); store_split(A1, 1); store_split(A2, 2);
                store_split(A3, 3); store_split(A4, 4); store_split(A5, 5);
            } else {       // feeds output layer only: raw f32 bits
                store_raw(A0, 0); store_raw(A1, 1); store_raw(A2, 2);
                store_raw(A3, 3); store_raw(A4, 4); store_raw(A5, 5);
            }
        }
        __syncthreads();
    }

    // ---------------- output layer (256 -> 2) + residual, fp32 VALU -----------
    #pragma unroll
    for (int d = 0; d < 24; ++d) {
        int k  = d / 12;            // compile-time per unrolled iter
        int rm = d % 12;            // compile-time per unrolled iter
        int p  = wv * 2 + k;        // point 0..15
        int c  = rm >> 1;
        int o  = rm & 1;
        int m  = c * PTS + p;
        int k0 = lane * 4;
        int idx = swz(m, k0);
        uint2 lo = *(const uint2*)&Ah[idx];
        uint2 hi = *(const uint2*)&Al[idx];
        float h0 = up0(lo.x, hi.x), h1 = up1(lo.x, hi.x);
        float h2 = up0(lo.y, hi.y), h3 = up1(lo.y, hi.y);
        float partial = h0 * W4[(k0 + 0) * 2 + o] + h1 * W4[(k0 + 1) * 2 + o]
                      + h2 * W4[(k0 + 2) * 2 + o] + h3 * W4[(k0 + 3) * 2 + o];
        #pragma unroll
        for (int off = 32; off > 0; off >>= 1)
            partial += __shfl_down(partial, off);
        if (lane == 0)
            red[p * 12 + rm] = partial + ((c == 0) ? b4[o] : 0.f);
    }
    __syncthreads();

    if (tid < PTS) {
        int p = tid;
        float u   = red[p * 12 + 0],  v   = red[p * 12 + 1];
        float ux  = red[p * 12 + 2],  vx  = red[p * 12 + 3];
        float uy  = red[p * 12 + 4],  vy  = red[p * 12 + 5];
        float ut  = red[p * 12 + 6],  vt  = red[p * 12 + 7];
        float uxx = red[p * 12 + 8],  vxx = red[p * 12 + 9];
        float uyy = red[p * 12 + 10], vyy = red[p * 12 + 11];
        float nuv = pin[3 * PTS + p];
        float fu = ut + u * ux + v * uy - nuv * (uxx + uyy);
        float fv = vt + u * vx + v * vy - nuv * (vxx + vyy);
        out[(p0 + p) * 2 + 0] = fu;
        out[(p0 + p) * 2 + 1] = fv;
    }
}

#define SMEM_BYTES (ROWS * 256 * 2 * 2 + PTS * 12 * 4 + 4 * PTS * 4)

extern "C" void kernel_launch(void* const* d_in, const int* in_sizes, int n_in,
                              void* d_out, int out_size, void* d_ws, size_t ws_size,
                              hipStream_t stream) {
    const float* x  = (const float*)d_in[0];
    const float* y  = (const float*)d_in[1];
    const float* t  = (const float*)d_in[2];
    const float* nu = (const float*)d_in[3];
    const float* W0 = (const float*)d_in[4];
    const float* b0 = (const float*)d_in[5];
    const float* W1 = (const float*)d_in[6];
    const float* b1 = (const float*)d_in[7];
    const float* W2 = (const float*)d_in[8];
    const float* b2 = (const float*)d_in[9];
    const float* W3 = (const float*)d_in[10];
    const float* b3 = (const float*)d_in[11];
    const float* W4 = (const float*)d_in[12];
    const float* b4 = (const float*)d_in[13];
    float* o = (float*)d_out;

    f16* bh = (f16*)d_ws;                          // 3*65536 f16 = 384 KB
    f16* bl = bh + 3 * (size_t)NLAYER_ELEMS;       // 384 KB more

    static bool s_attr_set = false;
    if (!s_attr_set) {
        hipFuncSetAttribute((const void*)pinn_burgers_kernel,
                            hipFuncAttributeMaxDynamicSharedMemorySize, SMEM_BYTES);
        s_attr_set = true;
    }

    hipLaunchKernelGGL(pack_weights, dim3(24), dim3(256), 0, stream, W1, W2, W3, bh, bl);
    hipLaunchKernelGGL(pinn_burgers_kernel, dim3(NPTS / PTS), dim3(512), SMEM_BYTES, stream,
                       x, y, t, nu, W0, b0, b1, b2, b3, W4, b4, bh, bl, o);
}

// Round 3
// 213.728 us; speedup vs baseline: 1.0555x; 1.0555x over previous
//
#include <hip/hip_runtime.h>

typedef _Float16 f16;
typedef _Float16 v8hf __attribute__((ext_vector_type(8)));
typedef _Float16 v4hf __attribute__((ext_vector_type(4)));
typedef _Float16 v2hf __attribute__((ext_vector_type(2)));
typedef float    v4f  __attribute__((ext_vector_type(4)));

#define NPTS 16384
#define PTS  8            // points per workgroup -> M = 6*PTS = 48 site-rows
#define NLAYER_ELEMS 65536  // 256*256 f16 per layer per split

// XOR-swizzled LDS index for logical (row m, f16-col j); row stride 256 f16
// (512 B == 0 mod 128 B). 16B chunks; phys chunk = chunk ^ (m&7). Every access
// in this kernel is contained in one 16B chunk, so data stays contiguous.
__device__ __forceinline__ int swz(int m, int j) {
    return m * 256 + ((((j >> 3) ^ (m & 7)) << 3) | (j & 7));
}

// ---- f32 <-> (lo16, hi16) bit-split helpers via v_perm_b32 (exact) ----------
__device__ __forceinline__ uint32_t pk_lo(float x0, float x1) {
    return __builtin_amdgcn_perm(__float_as_uint(x1), __float_as_uint(x0), 0x05040100u);
}
__device__ __forceinline__ uint32_t pk_hi(float x0, float x1) {
    return __builtin_amdgcn_perm(__float_as_uint(x1), __float_as_uint(x0), 0x07060302u);
}
__device__ __forceinline__ float up0(uint32_t lo, uint32_t hi) {
    return __uint_as_float(__builtin_amdgcn_perm(hi, lo, 0x05040100u));
}
__device__ __forceinline__ float up1(uint32_t lo, uint32_t hi) {
    return __uint_as_float(__builtin_amdgcn_perm(hi, lo, 0x07060302u));
}

// ---------------- prepass: split+transpose W1..W3 into MFMA A-operand order ----
// Bpack[L][ks][n][kk] (f16), kk=k&31, ks=k>>5: lane frag read = 8 contiguous f16.
// Grid 96 = (L, ks, kk-octet i): 4x the parallelism of the old 24-block version,
// 8 loads/thread instead of 32 (was a latency-bound ~50 us dispatch at 24 blocks).
__global__ void pack_weights(const float* __restrict__ W1, const float* __restrict__ W2,
                             const float* __restrict__ W3, f16* __restrict__ bh,
                             f16* __restrict__ bl) {
    const int b = blockIdx.x;
    const int L = b >> 5, r = b & 31, ks = r >> 2, i = r & 3;
    const int n = threadIdx.x;
    const float* W = (L == 0) ? W1 : (L == 1) ? W2 : W3;
    f16 h[8], l[8];
    #pragma unroll
    for (int j = 0; j < 8; ++j) {
        float w = W[(ks * 32 + i * 8 + j) * 256 + n];   // coalesced along n
        f16 hh = (f16)w;
        h[j] = hh;
        l[j] = (f16)(w - (float)hh);
    }
    size_t off = (size_t)L * NLAYER_ELEMS + (size_t)(ks * 256 + n) * 32 + (size_t)i * 8;
    *(v8hf*)(bh + off) = *(v8hf*)(h);
    *(v8hf*)(bl + off) = *(v8hf*)(l);
}

// ---------------- main kernel --------------------------------------------------
// (R1 structure, verbatim: PTS=8, 256 threads, 3 blocks/CU — best measured.)
// Channels: 0=val 1=dx 2=dy 3=dt 4=dxx 5=dyy; site-row m = c*PTS + p.
// Hidden GEMM computes Z^T via mfma(A-op=W^T frag, B-op=A^T frag):
//   D row (quad*4+reg) = neuron col n, D col (lane&15) = site-row m.
// Epilogue->activation hop carries raw f32 bits split across Ah(lo16)/Al(hi16);
// only activation outputs feeding a GEMM are converted to split-f16.
__global__ __launch_bounds__(256, 3) void pinn_burgers_kernel(
    const float* __restrict__ gx, const float* __restrict__ gy,
    const float* __restrict__ gt, const float* __restrict__ gnu,
    const float* __restrict__ W0, const float* __restrict__ b0,
    const float* __restrict__ b1, const float* __restrict__ b2,
    const float* __restrict__ b3,
    const float* __restrict__ W4, const float* __restrict__ b4,
    const f16* __restrict__ bh, const f16* __restrict__ bl,
    float* __restrict__ out)
{
    __shared__ f16 Ah[48 * 256];   // 24576 B, swizzled layout
    __shared__ f16 Al[48 * 256];   // 24576 B
    __shared__ float red[PTS][12];
    __shared__ float pin[4][PTS];

    const int tid  = threadIdx.x;
    const int lane = tid & 63;
    const int wv   = tid >> 6;        // 4 waves
    const int ln   = lane & 15;
    const int quad = lane >> 4;
    const int lnx  = ln & 7;
    const int p0   = blockIdx.x * PTS;

    if (tid < 4 * PTS) {
        int c = tid >> 3, p = tid & 7;
        const float* src = (c == 0) ? gx : (c == 1) ? gy : (c == 2) ? gt : gnu;
        pin[c][p] = src[p0 + p];
    }
    __syncthreads();

    // Activation-phase lane mapping: lane = (point pa, 8-col block jb).
    // Wave wv owns cols [wv*64, wv*64+64); all LDS traffic is b128.
    const int pa    = lane >> 3;          // point 0..7
    const int jb    = lane & 7;           // col block 0..7
    const int jbase = wv * 64 + jb * 8;   // first of 8 contiguous cols

    // split-f16 store of 8 activation values (feeds next GEMM)
    auto store_split = [&](const float (&A)[8], int c) {
        v8hf hh, ll;
        #pragma unroll
        for (int e = 0; e < 8; ++e) {
            f16 hv = (f16)A[e];
            hh[e] = hv;
            ll[e] = (f16)(A[e] - (float)hv);
        }
        int idx = swz(c * PTS + pa, jbase);
        *(v8hf*)&Ah[idx] = hh;
        *(v8hf*)&Al[idx] = ll;
    };
    // raw f32 bit-split store of 8 values (feeds output layer only)
    auto store_raw = [&](const float (&A)[8], int c) {
        uint4 lo, hi;
        lo.x = pk_lo(A[0], A[1]); lo.y = pk_lo(A[2], A[3]);
        lo.z = pk_lo(A[4], A[5]); lo.w = pk_lo(A[6], A[7]);
        hi.x = pk_hi(A[0], A[1]); hi.y = pk_hi(A[2], A[3]);
        hi.z = pk_hi(A[4], A[5]); hi.w = pk_hi(A[6], A[7]);
        int idx = swz(c * PTS + pa, jbase);
        *(uint4*)&Ah[idx] = lo;
        *(uint4*)&Al[idx] = hi;
    };

    // ---------------- layer 0 (4 -> 256), fp32 VALU, write split f16 ----------
    {
        v4f w0v[2], w1v[2], w2v[2], w3v[2], bbv[2];
        #pragma unroll
        for (int h = 0; h < 2; ++h) {
            w0v[h] = *(const v4f*)(W0 +   0 + jbase + 4 * h);
            w1v[h] = *(const v4f*)(W0 + 256 + jbase + 4 * h);
            w2v[h] = *(const v4f*)(W0 + 512 + jbase + 4 * h);
            w3v[h] = *(const v4f*)(W0 + 768 + jbase + 4 * h);
            bbv[h] = *(const v4f*)(b0 + jbase + 4 * h);
        }
        float hx = pin[0][pa];
        float hy = pin[1][pa];
        float ht = 2.f * pin[2][pa] - 1.f;
        float hn = 2.f * (pin[3][pa] - 0.01f) * (1.f / 0.09f) - 1.f;
        float A0[8], A1[8], A2[8], A3[8], A4[8], A5[8];
        #pragma unroll
        for (int e = 0; e < 8; ++e) {
            float w0 = w0v[e >> 2][e & 3];
            float w1 = w1v[e >> 2][e & 3];
            float w2 = w2v[e >> 2][e & 3];
            float w3 = w3v[e >> 2][e & 3];
            float z  = hx * w0 + hy * w1 + ht * w2 + hn * w3 + bbv[e >> 2][e & 3];
            float zx = w0, zy = w1, zt = 2.f * w2;
            float s  = 1.f / (1.f + __expf(-z));
            float g1 = s * (1.f + z * (1.f - s));
            float g2 = s * (1.f - s) * (2.f + z * (1.f - 2.f * s));
            A0[e] = z * s;
            A1[e] = g1 * zx; A2[e] = g1 * zy; A3[e] = g1 * zt;
            A4[e] = g2 * zx * zx; A5[e] = g2 * zy * zy;
        }
        store_split(A0, 0); store_split(A1, 1); store_split(A2, 2);
        store_split(A3, 3); store_split(A4, 4); store_split(A5, 5);
    }
    __syncthreads();

    // ---------------- hidden layers 1..3: split-f16 MFMA ----------------------
    const float* bias_ptr[3] = { b1, b2, b3 };
    for (int L = 0; L < 3; ++L) {
        const f16* __restrict__ bhL = bh + (size_t)L * NLAYER_ELEMS;
        const f16* __restrict__ blL = bl + (size_t)L * NLAYER_ELEMS;
        const float* __restrict__ bv = bias_ptr[L];

        v4f acc[4][3];     // [nTile t][mTile] ; wave owns neuron cols wv*64 .. wv*64+63
        #pragma unroll
        for (int t = 0; t < 4; ++t)
            #pragma unroll
            for (int mt = 0; mt < 3; ++mt)
                acc[t][mt] = (v4f){0.f, 0.f, 0.f, 0.f};

        #pragma unroll 2
        for (int ks = 0; ks < 8; ++ks) {
            // A-fragment LDS reads: chunk (4ks+quad) ^ (ln&7) -> conflict-free
            const int cb = (((4 * ks + quad) ^ lnx) << 3);
            v8hf a_h[3], a_l[3];
            #pragma unroll
            for (int mt = 0; mt < 3; ++mt) {
                const int rb = (mt * 16 + ln) * 256 + cb;
                a_h[mt] = *(const v8hf*)&Ah[rb];
                a_l[mt] = *(const v8hf*)&Al[rb];
            }
            v8hf w_h[4], w_l[4];
            #pragma unroll
            for (int t = 0; t < 4; ++t) {
                int n = wv * 64 + t * 16 + ln;
                size_t o = (size_t)(ks * 256 + n) * 32 + quad * 8;
                w_h[t] = *(const v8hf*)(bhL + o);
                w_l[t] = *(const v8hf*)(blL + o);
            }
            #pragma unroll
            for (int t = 0; t < 4; ++t)
                #pragma unroll
                for (int mt = 0; mt < 3; ++mt) {
                    acc[t][mt] = __builtin_amdgcn_mfma_f32_16x16x32_f16(w_h[t], a_h[mt], acc[t][mt], 0, 0, 0);
                    acc[t][mt] = __builtin_amdgcn_mfma_f32_16x16x32_f16(w_h[t], a_l[mt], acc[t][mt], 0, 0, 0);
                    acc[t][mt] = __builtin_amdgcn_mfma_f32_16x16x32_f16(w_l[t], a_h[mt], acc[t][mt], 0, 0, 0);
                }
        }
        __syncthreads();   // all reads of A done before overwrite

        // epilogue: D row = neuron n (quad*4+reg), D col = site-row m (lane&15).
        // Write raw f32 bits: lo16 -> Ah, hi16 -> Al (exact, cheap).
        #pragma unroll
        for (int t = 0; t < 4; ++t)
            #pragma unroll
            for (int mt = 0; mt < 3; ++mt) {
                v4f a = acc[t][mt];
                int nb = wv * 64 + t * 16 + quad * 4;
                int m  = mt * 16 + ln;
                if (mt == 0 && ln < PTS) {   // value-channel site rows get bias
                    const float4 bq = *(const float4*)(bv + nb);
                    a[0] += bq.x; a[1] += bq.y; a[2] += bq.z; a[3] += bq.w;
                }
                int idx = swz(m, nb);
                uint2 lo, hi;
                lo.x = pk_lo(a[0], a[1]); lo.y = pk_lo(a[2], a[3]);
                hi.x = pk_hi(a[0], a[1]); hi.y = pk_hi(a[2], a[3]);
                *(uint2*)&Ah[idx] = lo;
                *(uint2*)&Al[idx] = hi;
            }
        // NO barrier: activation below touches only this wave's columns.

        // activation + AD chain, in place (wave-local columns), b128 LDS
        {
            float z0[8], z1[8], z2[8], z3[8], z4[8], z5[8];
            auto load_z = [&](float (&Z)[8], int c) {
                int idx = swz(c * PTS + pa, jbase);
                uint4 lo = *(const uint4*)&Ah[idx];
                uint4 hi = *(const uint4*)&Al[idx];
                Z[0] = up0(lo.x, hi.x); Z[1] = up1(lo.x, hi.x);
                Z[2] = up0(lo.y, hi.y); Z[3] = up1(lo.y, hi.y);
                Z[4] = up0(lo.z, hi.z); Z[5] = up1(lo.z, hi.z);
                Z[6] = up0(lo.w, hi.w); Z[7] = up1(lo.w, hi.w);
            };
            load_z(z0, 0); load_z(z1, 1); load_z(z2, 2);
            load_z(z3, 3); load_z(z4, 4); load_z(z5, 5);

            float A0[8], g1[8], g2[8];
            #pragma unroll
            for (int e = 0; e < 8; ++e) {
                float zz = z0[e];
                float s  = 1.f / (1.f + __expf(-zz));
                A0[e] = zz * s;
                g1[e] = s * (1.f + zz * (1.f - s));
                g2[e] = s * (1.f - s) * (2.f + zz * (1.f - 2.f * s));
            }
            float A1[8], A2[8], A3[8], A4[8], A5[8];
            #pragma unroll
            for (int e = 0; e < 8; ++e) {
                A1[e] = g1[e] * z1[e];
                A2[e] = g1[e] * z2[e];
                A3[e] = g1[e] * z3[e];
                A4[e] = g2[e] * z1[e] * z1[e] + g1[e] * z4[e];
                A5[e] = g2[e] * z2[e] * z2[e] + g1[e] * z5[e];
            }
            if (L < 2) {   // feeds another MFMA layer: split f16
                store_split(A0, 0); store_split(A1, 1); store_split(A2, 2);
                store_split(A3, 3); store_split(A4, 4); store_split(A5, 5);
            } else {       // feeds output layer only: raw f32 bits
                store_raw(A0, 0); store_raw(A1, 1); store_raw(A2, 2);
                store_raw(A3, 3); store_raw(A4, 4); store_raw(A5, 5);
            }
        }
        __syncthreads();
    }

    // ---------------- output layer (256 -> 2) + residual, fp32 VALU -----------
    #pragma unroll
    for (int d = 0; d < 24; ++d) {
        int D  = wv * 24 + d;
        int p  = D / 12;
        int rm = D % 12;
        int c  = rm >> 1;
        int o  = rm & 1;
        int m  = c * PTS + p;
        int k0 = lane * 4;
        int idx = swz(m, k0);
        uint2 lo = *(const uint2*)&Ah[idx];
        uint2 hi = *(const uint2*)&Al[idx];
        float h0 = up0(lo.x, hi.x), h1 = up1(lo.x, hi.x);
        float h2 = up0(lo.y, hi.y), h3 = up1(lo.y, hi.y);
        float partial = h0 * W4[(k0 + 0) * 2 + o] + h1 * W4[(k0 + 1) * 2 + o]
                      + h2 * W4[(k0 + 2) * 2 + o] + h3 * W4[(k0 + 3) * 2 + o];
        #pragma unroll
        for (int off = 32; off > 0; off >>= 1)
            partial += __shfl_down(partial, off);
        if (lane == 0)
            red[p][rm] = partial + ((c == 0) ? b4[o] : 0.f);
    }
    __syncthreads();

    if (tid < PTS) {
        int p = tid;
        float u   = red[p][0],  v   = red[p][1];
        float ux  = red[p][2],  vx  = red[p][3];
        float uy  = red[p][4],  vy  = red[p][5];
        float ut  = red[p][6],  vt  = red[p][7];
        float uxx = red[p][8],  vxx = red[p][9];
        float uyy = red[p][10], vyy = red[p][11];
        float nuv = pin[3][p];
        float fu = ut + u * ux + v * uy - nuv * (uxx + uyy);
        float fv = vt + u * vx + v * vy - nuv * (vxx + vyy);
        out[(p0 + p) * 2 + 0] = fu;
        out[(p0 + p) * 2 + 1] = fv;
    }
}

extern "C" void kernel_launch(void* const* d_in, const int* in_sizes, int n_in,
                              void* d_out, int out_size, void* d_ws, size_t ws_size,
                              hipStream_t stream) {
    const float* x  = (const float*)d_in[0];
    const float* y  = (const float*)d_in[1];
    const float* t  = (const float*)d_in[2];
    const float* nu = (const float*)d_in[3];
    const float* W0 = (const float*)d_in[4];
    const float* b0 = (const float*)d_in[5];
    const float* W1 = (const float*)d_in[6];
    const float* b1 = (const float*)d_in[7];
    const float* W2 = (const float*)d_in[8];
    const float* b2 = (const float*)d_in[9];
    const float* W3 = (const float*)d_in[10];
    const float* b3 = (const float*)d_in[11];
    const float* W4 = (const float*)d_in[12];
    const float* b4 = (const float*)d_in[13];
    float* o = (float*)d_out;

    f16* bh = (f16*)d_ws;                          // 3*65536 f16 = 384 KB
    f16* bl = bh + 3 * (size_t)NLAYER_ELEMS;       // 384 KB more

    hipLaunchKernelGGL(pack_weights, dim3(96), dim3(256), 0, stream, W1, W2, W3, bh, bl);
    hipLaunchKernelGGL(pinn_burgers_kernel, dim3(NPTS / PTS), dim3(256), 0, stream,
                       x, y, t, nu, W0, b0, b1, b2, b3, W4, b4, bh, bl, o);
}